// Round 2
// baseline (391.107 us; speedup 1.0000x reference)
//
#include <hip/hip_runtime.h>
#include <hip/hip_bf16.h>

// Problem constants
constexpr int BB = 2, FF = 8, CIN = 16, COUT = 32, HH = 128, WW = 128;
constexpr int HW = HH * WW;          // 16384
constexpr int NIMG = BB * FF;        // 16
constexpr int TAPS = 16;
constexpr int TILE = 32, HALO = 2, LT = TILE + 2 * HALO;  // 36
constexpr int NSLOT = 256;           // 16 img * 16 tiles partial slots per channel

// Ring offsets in reference order, pre-biased: OFF[n] = (ox+2)*LT + (oy+2)
// OX = [-2 x5, -1,0,1, 2 x5, -1,0,1], OY = [-2..2, 2,2,2, -2..2, -2,-2,-2]
// OFF = {0,1,2,3,4, 40,76,112, 144,145,146,147,148, 36,72,108}; center = 2*36+2 = 74

template <int CI, bool PRE, bool XL>
__global__ __launch_bounds__(256)
void peak_conv(const float* __restrict__ in, const float* __restrict__ Wk,
               const float* __restrict__ bk, const float* __restrict__ prm,
               float* __restrict__ outp, float* __restrict__ P)
{
    __shared__ float tile[LT * LT];
    __shared__ float redS[4][8], redQ[4][8];

    const int tid    = threadIdx.x;
    const int tileid = blockIdx.x;        // 0..15  (4x4 tiles of 32x32)
    const int img    = blockIdx.y;        // 0..15
    const int ocb    = blockIdx.z * 8;    // output-channel base
    const int tx     = (tileid & 3) * TILE;   // w origin
    const int ty     = (tileid >> 2) * TILE;  // h origin
    const int col    = tid & 31;
    const int row0   = tid >> 5;          // 0..7

    const int OFF[16] = {0,1,2,3,4, 40,76,112, 144,145,146,147,148, 36,72,108};

    float acc[4][8];
#pragma unroll
    for (int k = 0; k < 4; ++k)
#pragma unroll
        for (int oo = 0; oo < 8; ++oo) acc[k][oo] = 0.f;

    for (int c = 0; c < CI; ++c) {
        const float* src;
        if (XL)  // x layout (B, CIN, F, H, W); img = b*F+f
            src = in + (size_t)(((img >> 3) * CI + c) * FF + (img & 7)) * HW;
        else     // (img, CI, H, W)
            src = in + (size_t)(img * CI + c) * HW;

        float pa = 0.f, pb = 0.f;
        if (PRE) { pa = prm[c]; pb = prm[COUT + c]; }

        __syncthreads();
        for (int idx = tid; idx < LT * LT; idx += 256) {
            int r  = idx / LT;
            int cc = idx - r * LT;
            int gh = ty + r - HALO, gw = tx + cc - HALO;
            float v = 0.f;
            if ((unsigned)gh < (unsigned)HH && (unsigned)gw < (unsigned)WW) {
                v = src[gh * WW + gw];
                if (PRE) { v = fmaf(pa, v, pb); v = (v >= 0.f) ? v : 0.01f * v; }
            }
            tile[idx] = v;
        }
        __syncthreads();

        const float* wrow = Wk + (size_t)ocb * CI * TAPS + c * TAPS; // W[ocb][c][0]
#pragma unroll
        for (int k = 0; k < 4; ++k) {
            const int lr = row0 + 8 * k;                  // window top-left row
            const float* bp = &tile[lr * LT + col];       // window top-left
            float ctr = bp[74];
#pragma unroll
            for (int n = 0; n < 16; ++n) {
                float d = ctr - bp[OFF[n]];
#pragma unroll
                for (int oo = 0; oo < 8; ++oo)
                    acc[k][oo] = fmaf(wrow[oo * CI * TAPS + n], d, acc[k][oo]);
            }
        }
    }

    // epilogue: bias add, store, per-channel partial sums for BN stats
    const int slot = img * 16 + tileid;
    float ssum[8], ssq[8];
#pragma unroll
    for (int oo = 0; oo < 8; ++oo) { ssum[oo] = 0.f; ssq[oo] = 0.f; }

#pragma unroll
    for (int k = 0; k < 4; ++k) {
        int gh = ty + row0 + 8 * k;
        int gw = tx + col;
#pragma unroll
        for (int oo = 0; oo < 8; ++oo) {
            float v = acc[k][oo] + bk[ocb + oo];
            outp[(size_t)(img * COUT + ocb + oo) * HW + gh * WW + gw] = v;
            ssum[oo] += v;
            ssq[oo]  = fmaf(v, v, ssq[oo]);
        }
    }

    const int lane = tid & 63, wid = tid >> 6;
#pragma unroll
    for (int oo = 0; oo < 8; ++oo) {
        float s = ssum[oo], q = ssq[oo];
#pragma unroll
        for (int m = 32; m >= 1; m >>= 1) {
            s += __shfl_xor(s, m);
            q += __shfl_xor(q, m);
        }
        if (lane == 0) { redS[wid][oo] = s; redQ[wid][oo] = q; }
    }
    __syncthreads();
    if (tid < 8) {
        float s = redS[0][tid] + redS[1][tid] + redS[2][tid] + redS[3][tid];
        P[(size_t)(ocb + tid) * NSLOT + slot] = s;
    } else if (tid < 16) {
        int oo = tid - 8;
        float q = redQ[0][oo] + redQ[1][oo] + redQ[2][oo] + redQ[3][oo];
        P[(size_t)COUT * NSLOT + (size_t)(ocb + oo) * NSLOT + slot] = q;
    }
}

// One block per channel: reduce 256 partial sums/sumsq -> affine params a,b
__global__ __launch_bounds__(256)
void bn_stats(const float* __restrict__ P, const float* __restrict__ gamma,
              const float* __restrict__ beta, float* __restrict__ prm)
{
    __shared__ float rs[256], rq[256];
    const int c = blockIdx.x, tid = threadIdx.x;
    rs[tid] = P[(size_t)c * NSLOT + tid];
    rq[tid] = P[(size_t)COUT * NSLOT + (size_t)c * NSLOT + tid];
    __syncthreads();
    for (int s = 128; s > 0; s >>= 1) {
        if (tid < s) { rs[tid] += rs[tid + s]; rq[tid] += rq[tid + s]; }
        __syncthreads();
    }
    if (tid == 0) {
        const float n  = (float)(NIMG * HW);   // 262144
        float mu  = rs[0] / n;
        float var = rq[0] / n - mu * mu;
        float a   = gamma[c] * rsqrtf(var + 1e-5f);
        prm[c]        = a;
        prm[COUT + c] = beta[c] - mu * a;
    }
}

// BN2 + leaky + "mean over F" with the reference's FLAT-RESHAPE semantics:
//   y(16,32,H,W) reshaped flat to (B,COUT,F,H,W):
//   out[b][o][p] = (1/8) sum_f leaky(bn2( t2[ img=b*8+(o>>2) ][ c=(o&3)*8+f ][p] ))
__global__ __launch_bounds__(256)
void finalize(const float* __restrict__ t2, const float* __restrict__ prm,
              float* __restrict__ outp)
{
    int gid = blockIdx.x * 256 + threadIdx.x;   // < B*COUT*HW = 1048576
    int p    = gid & (HW - 1);
    int rest = gid >> 14;
    int o    = rest & 31;
    int b    = rest >> 5;
    int img  = b * 8 + (o >> 2);
    int cb   = (o & 3) * 8;
    float s  = 0.f;
#pragma unroll
    for (int f = 0; f < FF; ++f) {
        int c   = cb + f;
        float a = prm[c], bb = prm[COUT + c];
        float v = t2[(size_t)(img * COUT + c) * HW + p];
        v = fmaf(a, v, bb);
        s += (v >= 0.f) ? v : 0.01f * v;
    }
    outp[gid] = 0.125f * s;
}

extern "C" void kernel_launch(void* const* d_in, const int* in_sizes, int n_in,
                              void* d_out, int out_size, void* d_ws, size_t ws_size,
                              hipStream_t stream)
{
    const float* x   = (const float*)d_in[0];
    const float* W1  = (const float*)d_in[1];
    const float* b1  = (const float*)d_in[2];
    const float* g1  = (const float*)d_in[3];
    const float* be1 = (const float*)d_in[4];
    const float* W2  = (const float*)d_in[5];
    const float* b2  = (const float*)d_in[6];
    const float* g2  = (const float*)d_in[7];
    const float* be2 = (const float*)d_in[8];
    float* out = (float*)d_out;

    float* ws   = (float*)d_ws;
    const size_t TSZ = (size_t)NIMG * COUT * HW;  // 8388608 floats = 32 MB
    float* t1   = ws;
    float* t2   = t1 + TSZ;
    float* P1   = t2 + TSZ;                        // [2][COUT][NSLOT]
    float* P2   = P1 + 2 * COUT * NSLOT;
    float* prm1 = P2 + 2 * COUT * NSLOT;           // a[32], b[32]
    float* prm2 = prm1 + 2 * COUT;

    dim3 cgrid(16, NIMG, 4);
    peak_conv<CIN, false, true ><<<cgrid, 256, 0, stream>>>(x,  W1, b1, nullptr, t1, P1);
    bn_stats<<<COUT, 256, 0, stream>>>(P1, g1, be1, prm1);
    peak_conv<COUT, true, false><<<cgrid, 256, 0, stream>>>(t1, W2, b2, prm1,   t2, P2);
    bn_stats<<<COUT, 256, 0, stream>>>(P2, g2, be2, prm2);
    finalize<<<(BB * COUT * HW) / 256, 256, 0, stream>>>(t2, prm2, out);
}